// Round 9
// baseline (303.311 us; speedup 1.0000x reference)
//
#include <hip/hip_runtime.h>
#include <math.h>

#define HEADS 4
#define DHEAD 128
#define NPOS  4096      // 64*64 spatial positions
#define CIN   256
#define SCALEF 0.08838834764831845f   // 128^-0.5
#define LOG2E  1.4426950408889634f
#define QSCALE (SCALEF * LOG2E)       // folded: exp(sim) == exp2(sim * log2e)

typedef _Float16 half8  __attribute__((ext_vector_type(8)));
typedef _Float16 half4  __attribute__((ext_vector_type(4)));
typedef float    f32x4  __attribute__((ext_vector_type(4)));

// Fragment layout for a matrix consumed as a 16x16x32 MFMA operand:
//   frag[rowtile = row>>4][kb = col>>5][lane = ((col>>3)&3)*16 + (row&15)][elem = col&7]
// One (rowtile,kb) slab = 64 lanes * 8 halves = 1 KiB -> wave loads are a
// single contiguous 1 KiB transaction (l*16B each lane).
#define FRAG_HEAD_HALVES (256 * 4 * 512)   // 524288 halves = 1 MB per head

// ---------------------------------------------------------------------------
// Kernel 0: convert W -> fp16 (QSCALE folded into Q rows), fmap -> fp16
// transposed [p][c] for proj's B-operand.
// ---------------------------------------------------------------------------
__global__ __launch_bounds__(256) void cvt_kernel(const float* __restrict__ fmap,
                                                  const float* __restrict__ W,
                                                  _Float16* __restrict__ W16,
                                                  _Float16* __restrict__ fmapT) {
  if (blockIdx.x < 16) {
    int base = blockIdx.x * 16384 + threadIdx.x;
#pragma unroll
    for (int t = 0; t < 64; ++t) {
      int idx = base + t * 256;
      float v = W[idx];
      W16[idx] = (_Float16)(idx < 512 * CIN ? v * QSCALE : v);
    }
  } else {
    int tile = blockIdx.x - 16;       // 64 p-tiles x 4 c-tiles
    int p0 = (tile >> 2) * 64, c0 = (tile & 3) * 64;
    __shared__ float t_lds[64][65];
    int tid = threadIdx.x;
#pragma unroll
    for (int t = 0; t < 16; ++t) {
      int lin = tid + t * 256;
      int r = lin >> 6, col = lin & 63;
      t_lds[r][col] = fmap[(size_t)(c0 + r) * NPOS + p0 + col];
    }
    __syncthreads();
#pragma unroll
    for (int t = 0; t < 16; ++t) {
      int lin = tid + t * 256;
      int pr = lin >> 6, cc = lin & 63;
      fmapT[(size_t)(p0 + pr) * CIN + c0 + cc] = (_Float16)t_lds[cc][pr];
    }
  }
}

// ---------------------------------------------------------------------------
// Kernel 1: projection GEMM.  qk[o][p] = sum_c W16[o][c]*fmapT[p][c]
// Output written in FRAGMENT layout (qf / kf) for the attn kernel.
// ---------------------------------------------------------------------------
__global__ __launch_bounds__(256) void proj_mfma(const _Float16* __restrict__ W16,
                                                 const _Float16* __restrict__ fmapT,
                                                 _Float16* __restrict__ qf,
                                                 _Float16* __restrict__ kf) {
  const int p0 = blockIdx.x * 64;
  const int o0 = blockIdx.y * 64 + (threadIdx.x >> 6) * 16;
  const int l = threadIdx.x & 63;
  const int lr = l & 15, lg = l >> 4;

  const f32x4 z = {0.f, 0.f, 0.f, 0.f};
  f32x4 acc[4] = {z, z, z, z};
#pragma unroll
  for (int kb = 0; kb < 8; ++kb) {
    half8 a = *(const half8*)(W16 + (size_t)(o0 + lr) * CIN + kb * 32 + lg * 8);
#pragma unroll
    for (int j = 0; j < 4; ++j) {
      half8 b = *(const half8*)(fmapT + (size_t)(p0 + j * 16 + lr) * CIN + kb * 32 + lg * 8);
      acc[j] = __builtin_amdgcn_mfma_f32_16x16x32_f16(a, b, acc[j], 0, 0, 0);
    }
  }
  // C/D: col(p) = lr, row(o) = lg*4 + r.  4 consecutive d per lane.
  const int ob = o0 + lg * 4;
  const bool isq = ob < 512;
  const int oo = isq ? ob : ob - 512;
  const int h = oo >> 7, db = oo & 127;        // d base, multiple of 4
  const int kb2 = db >> 5;                     // frag kb
  const int flane = ((db >> 3) & 3) * 16 + lr; // frag lane (lr = p&15)
  const int e0 = db & 7;                       // 0 or 4
  _Float16* dst = (isq ? qf : kf) + (size_t)h * FRAG_HEAD_HALVES;
#pragma unroll
  for (int j = 0; j < 4; ++j) {
    int pt = (p0 >> 4) + j;                    // position tile
    half4 v = {(_Float16)acc[j][0], (_Float16)acc[j][1],
               (_Float16)acc[j][2], (_Float16)acc[j][3]};
    *(half4*)(dst + ((size_t)pt * 4 + kb2) * 512 + flane * 8 + e0) = v;
  }
}

// ---------------------------------------------------------------------------
// Kernel 2: fused sim + softmax, TWO-PASS RECOMPUTE (no P storage).
// Block = (head, 64 q-rows = 4 row-tiles), 1024 thr / 16 waves; wave owns a
// 256-col strip.  Pass 1: QK^T + exp2, row-sums only.  Block reduce.
// Pass 2: recompute QK^T + exp2, scale by 1/rowsum, write directly.
// K read volume halves vs QROWS=16 (64 blocks/head instead of 256).
// ---------------------------------------------------------------------------
#define QROWS 64
#define RT    4     // row tiles per block
#define NTIL  16    // 256 cols per wave strip

__global__ __launch_bounds__(1024) void attn_mfma(const _Float16* __restrict__ qf,
                                                  const _Float16* __restrict__ kf,
                                                  float* __restrict__ out) {
  const int h = blockIdx.y;
  const int i0 = blockIdx.x * QROWS;
  const int wv = threadIdx.x >> 6;
  const int l = threadIdx.x & 63;
  const int lr = l & 15, lg = l >> 4;

  const _Float16* Qf = qf + (size_t)h * FRAG_HEAD_HALVES;
  const _Float16* Kf = kf + (size_t)h * FRAG_HEAD_HALVES;

  // A fragments for 4 row-tiles (64 VGPRs), hoisted for whole kernel
  half8 afr[RT][4];
#pragma unroll
  for (int rt = 0; rt < RT; ++rt)
#pragma unroll
    for (int kb = 0; kb < 4; ++kb)
      afr[rt][kb] = *(const half8*)(Qf + (((size_t)(i0 >> 4) + rt) * 4 + kb) * 512 + l * 8);

  const int jt0 = wv * NTIL;      // first column tile for this wave
  const _Float16* kbase = Kf + (size_t)jt0 * 2048 + l * 8;

  float rs[RT][4];
#pragma unroll
  for (int rt = 0; rt < RT; ++rt)
#pragma unroll
    for (int r = 0; r < 4; ++r) rs[rt][r] = 0.f;
  const f32x4 z = {0.f, 0.f, 0.f, 0.f};

  // ---------------- pass 1: row sums only ----------------
#pragma unroll
  for (int t = 0; t < NTIL; ++t) {
    const _Float16* kp = kbase + (size_t)t * 2048;
    half8 b0 = *(const half8*)(kp);
    half8 b1 = *(const half8*)(kp + 512);
    half8 b2 = *(const half8*)(kp + 1024);
    half8 b3 = *(const half8*)(kp + 1536);
#pragma unroll
    for (int rt = 0; rt < RT; ++rt) {
      f32x4 acc = z;
      __builtin_amdgcn_s_setprio(1);
      acc = __builtin_amdgcn_mfma_f32_16x16x32_f16(afr[rt][0], b0, acc, 0, 0, 0);
      acc = __builtin_amdgcn_mfma_f32_16x16x32_f16(afr[rt][1], b1, acc, 0, 0, 0);
      acc = __builtin_amdgcn_mfma_f32_16x16x32_f16(afr[rt][2], b2, acc, 0, 0, 0);
      acc = __builtin_amdgcn_mfma_f32_16x16x32_f16(afr[rt][3], b3, acc, 0, 0, 0);
      __builtin_amdgcn_s_setprio(0);
      rs[rt][0] += __builtin_amdgcn_exp2f(acc[0]);
      rs[rt][1] += __builtin_amdgcn_exp2f(acc[1]);
      rs[rt][2] += __builtin_amdgcn_exp2f(acc[2]);
      rs[rt][3] += __builtin_amdgcn_exp2f(acc[3]);
    }
  }

  // reduce across the 16 lanes (lr bits) of each row group
#pragma unroll
  for (int off = 1; off < 16; off <<= 1) {
#pragma unroll
    for (int rt = 0; rt < RT; ++rt)
#pragma unroll
      for (int r = 0; r < 4; ++r) rs[rt][r] += __shfl_xor(rs[rt][r], off);
  }
  __shared__ float red[16][QROWS];
  if (lr == 0) {
#pragma unroll
    for (int rt = 0; rt < RT; ++rt)
#pragma unroll
      for (int r = 0; r < 4; ++r) red[wv][rt * 16 + lg * 4 + r] = rs[rt][r];
  }
  __syncthreads();
  float inv[RT][4];
#pragma unroll
  for (int rt = 0; rt < RT; ++rt)
#pragma unroll
    for (int r = 0; r < 4; ++r) {
      float s = 0.f;
#pragma unroll
      for (int w = 0; w < 16; ++w) s += red[w][rt * 16 + lg * 4 + r];
      inv[rt][r] = 1.0f / s;
    }

  // ---------------- pass 2: recompute, normalize, write ----------------
  float* ob = out + ((size_t)h * NPOS + i0) * NPOS + jt0 * 16;
#pragma unroll
  for (int t = 0; t < NTIL; ++t) {
    const _Float16* kp = kbase + (size_t)t * 2048;
    half8 b0 = *(const half8*)(kp);
    half8 b1 = *(const half8*)(kp + 512);
    half8 b2 = *(const half8*)(kp + 1024);
    half8 b3 = *(const half8*)(kp + 1536);
#pragma unroll
    for (int rt = 0; rt < RT; ++rt) {
      f32x4 acc = z;
      __builtin_amdgcn_s_setprio(1);
      acc = __builtin_amdgcn_mfma_f32_16x16x32_f16(afr[rt][0], b0, acc, 0, 0, 0);
      acc = __builtin_amdgcn_mfma_f32_16x16x32_f16(afr[rt][1], b1, acc, 0, 0, 0);
      acc = __builtin_amdgcn_mfma_f32_16x16x32_f16(afr[rt][2], b2, acc, 0, 0, 0);
      acc = __builtin_amdgcn_mfma_f32_16x16x32_f16(afr[rt][3], b3, acc, 0, 0, 0);
      __builtin_amdgcn_s_setprio(0);
      float* obr = ob + (size_t)(rt * 16 + lg * 4) * NPOS + t * 16 + lr;
      obr[0]            = __builtin_amdgcn_exp2f(acc[0]) * inv[rt][0];
      obr[NPOS]         = __builtin_amdgcn_exp2f(acc[1]) * inv[rt][1];
      obr[2 * (size_t)NPOS] = __builtin_amdgcn_exp2f(acc[2]) * inv[rt][2];
      obr[3 * (size_t)NPOS] = __builtin_amdgcn_exp2f(acc[3]) * inv[rt][3];
    }
  }
}

extern "C" void kernel_launch(void* const* d_in, const int* in_sizes, int n_in,
                              void* d_out, int out_size, void* d_ws, size_t ws_size,
                              hipStream_t stream) {
  const float* fmap = (const float*)d_in[0];   // [1,256,64,64]
  const float* W    = (const float*)d_in[1];   // [1024,256]
  float* out = (float*)d_out;                  // [1,4,4096,4096]

  char* ws = (char*)d_ws;
  _Float16* qf    = (_Float16*)(ws);                    // 4 MB fragment layout
  _Float16* kf    = (_Float16*)(ws + (4u << 20));       // 4 MB fragment layout
  _Float16* W16   = (_Float16*)(ws + (8u << 20));       // 512 KB
  _Float16* fmapT = (_Float16*)(ws + (8u << 20) + (512u << 10)); // 2 MB

  cvt_kernel<<<272, 256, 0, stream>>>(fmap, W, W16, fmapT);
  proj_mfma<<<dim3(NPOS / 64, 1024 / 64), 256, 0, stream>>>(W16, fmapT, qf, kf);
  attn_mfma<<<dim3(NPOS / QROWS, HEADS), 1024, 0, stream>>>(qf, kf, out);
}

// Round 10
// 107.034 us; speedup vs baseline: 2.8338x; 2.8338x over previous
//
#include <hip/hip_runtime.h>
#include <math.h>

#define HEADS 4
#define DHEAD 128
#define NPOS  4096      // 64*64 spatial positions
#define CIN   256
#define SCALEF 0.08838834764831845f   // 128^-0.5
#define LOG2E  1.4426950408889634f
#define QSCALE (SCALEF * LOG2E)       // folded: exp(sim) == exp2(sim * log2e)

typedef _Float16 half8  __attribute__((ext_vector_type(8)));
typedef _Float16 half4  __attribute__((ext_vector_type(4)));
typedef _Float16 half2v __attribute__((ext_vector_type(2)));
typedef float    f32x4  __attribute__((ext_vector_type(4)));

// Fragment layout for a matrix consumed as a 16x16x32 MFMA operand:
//   frag[rowtile = row>>4][kb = col>>5][lane = ((col>>3)&3)*16 + (row&15)][elem = col&7]
// One (rowtile,kb) slab = 64 lanes * 8 halves = 1 KiB -> wave loads are a
// single contiguous 1 KiB transaction (l*16B each lane).
#define FRAG_HEAD_HALVES (256 * 4 * 512)   // 524288 halves = 1 MB per head

// ---------------------------------------------------------------------------
// Kernel 0: convert W -> fp16 (QSCALE folded into Q rows), fmap -> fp16
// transposed [p][c] for proj's B-operand.
// ---------------------------------------------------------------------------
__global__ __launch_bounds__(256) void cvt_kernel(const float* __restrict__ fmap,
                                                  const float* __restrict__ W,
                                                  _Float16* __restrict__ W16,
                                                  _Float16* __restrict__ fmapT) {
  if (blockIdx.x < 16) {
    int base = blockIdx.x * 16384 + threadIdx.x;
#pragma unroll
    for (int t = 0; t < 64; ++t) {
      int idx = base + t * 256;
      float v = W[idx];
      W16[idx] = (_Float16)(idx < 512 * CIN ? v * QSCALE : v);
    }
  } else {
    int tile = blockIdx.x - 16;       // 64 p-tiles x 4 c-tiles
    int p0 = (tile >> 2) * 64, c0 = (tile & 3) * 64;
    __shared__ float t_lds[64][65];
    int tid = threadIdx.x;
#pragma unroll
    for (int t = 0; t < 16; ++t) {
      int lin = tid + t * 256;
      int r = lin >> 6, col = lin & 63;
      t_lds[r][col] = fmap[(size_t)(c0 + r) * NPOS + p0 + col];
    }
    __syncthreads();
#pragma unroll
    for (int t = 0; t < 16; ++t) {
      int lin = tid + t * 256;
      int pr = lin >> 6, cc = lin & 63;
      fmapT[(size_t)(p0 + pr) * CIN + c0 + cc] = (_Float16)t_lds[cc][pr];
    }
  }
}

// ---------------------------------------------------------------------------
// Kernel 1: projection GEMM.  qk[o][p] = sum_c W16[o][c]*fmapT[p][c]
// Output written in FRAGMENT layout (qf / kf) for the attn kernel.
// ---------------------------------------------------------------------------
__global__ __launch_bounds__(256) void proj_mfma(const _Float16* __restrict__ W16,
                                                 const _Float16* __restrict__ fmapT,
                                                 _Float16* __restrict__ qf,
                                                 _Float16* __restrict__ kf) {
  const int p0 = blockIdx.x * 64;
  const int o0 = blockIdx.y * 64 + (threadIdx.x >> 6) * 16;
  const int l = threadIdx.x & 63;
  const int lr = l & 15, lg = l >> 4;

  const f32x4 z = {0.f, 0.f, 0.f, 0.f};
  f32x4 acc[4] = {z, z, z, z};
#pragma unroll
  for (int kb = 0; kb < 8; ++kb) {
    half8 a = *(const half8*)(W16 + (size_t)(o0 + lr) * CIN + kb * 32 + lg * 8);
#pragma unroll
    for (int j = 0; j < 4; ++j) {
      half8 b = *(const half8*)(fmapT + (size_t)(p0 + j * 16 + lr) * CIN + kb * 32 + lg * 8);
      acc[j] = __builtin_amdgcn_mfma_f32_16x16x32_f16(a, b, acc[j], 0, 0, 0);
    }
  }
  // C/D: col(p) = lr, row(o) = lg*4 + r.  4 consecutive d per lane.
  const int ob = o0 + lg * 4;
  const bool isq = ob < 512;
  const int oo = isq ? ob : ob - 512;
  const int h = oo >> 7, db = oo & 127;        // d base, multiple of 4
  const int kb2 = db >> 5;                     // frag kb
  const int flane = ((db >> 3) & 3) * 16 + lr; // frag lane (lr = p&15)
  const int e0 = db & 7;                       // 0 or 4
  _Float16* dst = (isq ? qf : kf) + (size_t)h * FRAG_HEAD_HALVES;
#pragma unroll
  for (int j = 0; j < 4; ++j) {
    int pt = (p0 >> 4) + j;                    // position tile
    half4 v = {(_Float16)acc[j][0], (_Float16)acc[j][1],
               (_Float16)acc[j][2], (_Float16)acc[j][3]};
    *(half4*)(dst + ((size_t)pt * 4 + kb2) * 512 + flane * 8 + e0) = v;
  }
}

// ---------------------------------------------------------------------------
// Kernel 2: fused sim + softmax via MFMA, fragment-layout operands.
// R7 structure exactly (512 thr / 8 waves / 512-col strips, VGPR~100, exp2,
// setprio, NORMAL stores) + XCD-locality swizzle ONLY: flat 1024-block grid,
// head = (b&7)>>1 -> each head's 256 blocks land on one XCD pair (round-robin
// dispatch assumption), so each XCD L2 holds just that head's K+Q (2 MB) and
// the 1 GB of K re-reads become L2 hits instead of L3 traffic.
// ---------------------------------------------------------------------------
#define QROWS 16
#define NTIL  32    // 512 cols per wave strip

__global__ __launch_bounds__(512) void attn_mfma(const _Float16* __restrict__ qf,
                                                 const _Float16* __restrict__ kf,
                                                 float* __restrict__ out) {
  // XCD-locality decode (bijective: 1024 blocks, 1024 % 8 == 0)
  const int b = blockIdx.x;            // 0..1023
  const int h = (b & 7) >> 1;          // head on XCD pair {2h, 2h+1}
  const int qtile = ((b >> 3) << 1) | (b & 1);   // 0..255, bijective per head
  const int i0 = qtile * QROWS;

  const int wv = threadIdx.x >> 6;
  const int l = threadIdx.x & 63;
  const int lr = l & 15, lg = l >> 4;

  const _Float16* Qf = qf + (size_t)h * FRAG_HEAD_HALVES;
  const _Float16* Kf = kf + (size_t)h * FRAG_HEAD_HALVES;

  // A fragments (Q row-tile i0>>4), hoisted
  half8 afr[4];
#pragma unroll
  for (int kb = 0; kb < 4; ++kb)
    afr[kb] = *(const half8*)(Qf + ((size_t)(i0 >> 4) * 4 + kb) * 512 + l * 8);

  const int jt0 = wv * NTIL;      // first column tile for this wave
  half2v Pst[2 * NTIL];
  float rs[4] = {0.f, 0.f, 0.f, 0.f};
  const f32x4 z = {0.f, 0.f, 0.f, 0.f};

#pragma unroll
  for (int t = 0; t < NTIL; ++t) {
    const _Float16* kp = Kf + ((size_t)(jt0 + t) * 4) * 512 + l * 8;
    half8 b0 = *(const half8*)(kp);
    half8 b1 = *(const half8*)(kp + 512);
    half8 b2 = *(const half8*)(kp + 1024);
    half8 b3 = *(const half8*)(kp + 1536);
    f32x4 acc = z;
    __builtin_amdgcn_s_setprio(1);
    acc = __builtin_amdgcn_mfma_f32_16x16x32_f16(afr[0], b0, acc, 0, 0, 0);
    acc = __builtin_amdgcn_mfma_f32_16x16x32_f16(afr[1], b1, acc, 0, 0, 0);
    acc = __builtin_amdgcn_mfma_f32_16x16x32_f16(afr[2], b2, acc, 0, 0, 0);
    acc = __builtin_amdgcn_mfma_f32_16x16x32_f16(afr[3], b3, acc, 0, 0, 0);
    __builtin_amdgcn_s_setprio(0);
    // Q was pre-scaled by log2e: exp(sim) == exp2(acc), one v_exp each.
    float e0 = __builtin_amdgcn_exp2f(acc[0]);
    float e1 = __builtin_amdgcn_exp2f(acc[1]);
    float e2 = __builtin_amdgcn_exp2f(acc[2]);
    float e3 = __builtin_amdgcn_exp2f(acc[3]);
    rs[0] += e0; rs[1] += e1; rs[2] += e2; rs[3] += e3;
    Pst[2 * t]     = half2v{(_Float16)e0, (_Float16)e1};
    Pst[2 * t + 1] = half2v{(_Float16)e2, (_Float16)e3};
  }

  // Row sums: reduce across the 16 lanes (lr bits) of each row group
#pragma unroll
  for (int off = 1; off < 16; off <<= 1) {
#pragma unroll
    for (int r = 0; r < 4; ++r) rs[r] += __shfl_xor(rs[r], off);
  }
  __shared__ float red[8][16];
  if (lr == 0) {
#pragma unroll
    for (int r = 0; r < 4; ++r) red[wv][lg * 4 + r] = rs[r];
  }
  __syncthreads();
  float inv[4];
#pragma unroll
  for (int r = 0; r < 4; ++r) {
    float s = 0.f;
#pragma unroll
    for (int w = 0; w < 8; ++w) s += red[w][lg * 4 + r];
    inv[r] = 1.0f / s;
  }

  // Normalized write (normal stores). row = lg*4 + r, col = (jt0+t)*16 + lr.
  float* ob = out + ((size_t)h * NPOS + i0) * NPOS + jt0 * 16;
#pragma unroll
  for (int t = 0; t < NTIL; ++t) {
    float e[4] = {(float)Pst[2 * t][0], (float)Pst[2 * t][1],
                  (float)Pst[2 * t + 1][0], (float)Pst[2 * t + 1][1]};
#pragma unroll
    for (int r = 0; r < 4; ++r) {
      ob[(size_t)(lg * 4 + r) * NPOS + t * 16 + lr] = e[r] * inv[r];
    }
  }
}

extern "C" void kernel_launch(void* const* d_in, const int* in_sizes, int n_in,
                              void* d_out, int out_size, void* d_ws, size_t ws_size,
                              hipStream_t stream) {
  const float* fmap = (const float*)d_in[0];   // [1,256,64,64]
  const float* W    = (const float*)d_in[1];   // [1024,256]
  float* out = (float*)d_out;                  // [1,4,4096,4096]

  char* ws = (char*)d_ws;
  _Float16* qf    = (_Float16*)(ws);                    // 4 MB fragment layout
  _Float16* kf    = (_Float16*)(ws + (4u << 20));       // 4 MB fragment layout
  _Float16* W16   = (_Float16*)(ws + (8u << 20));       // 512 KB
  _Float16* fmapT = (_Float16*)(ws + (8u << 20) + (512u << 10)); // 2 MB

  cvt_kernel<<<272, 256, 0, stream>>>(fmap, W, W16, fmapT);
  proj_mfma<<<dim3(NPOS / 64, 1024 / 64), 256, 0, stream>>>(W16, fmapT, qf, kf);
  attn_mfma<<<NPOS / QROWS * HEADS, 512, 0, stream>>>(qf, kf, out);
}